// Round 1
// baseline (817.240 us; speedup 1.0000x reference)
//
#include <hip/hip_runtime.h>
#include <math.h>

#define H 8
#define KK 2048
#define DD 64
#define HIDN 1024
#define BB 8192
#define TWO_D 128
#define OO 128

// ws float-element offsets
#define WS_CT    0            // H*DD*KK = 1048576 (codebooks transposed [h][d][k])
#define WS_CSQ   1048576      // H*KK
#define WS_ZSQ   1064960      // BB*H
#define WS_IDX   1130496      // BB*H (int)
#define WS_AVGP  1196032      // H*KK
#define WS_HIST  1212416      // H*KK (uint)
#define WS_ACC   1228800      // 2 doubles: commit_acc, ortho_acc
#define WS_ZERO_BYTES ((16384 + 16384 + 4) * 4)

// out float-element offsets
#define OUT_ZQ 0
#define OUT_IDX 8388608
#define OUT_COMMIT 8454144
#define OUT_CBL 8454145
#define OUT_ENT 8454146
#define OUT_ORTHO 8454147
#define OUT_ZH 8454148

// ---------------- k_pre: c_sq + transpose codebooks to [h][d][k] ----------------
__global__ __launch_bounds__(256) void k_pre(const float* __restrict__ cb, float* __restrict__ ws) {
    int h = blockIdx.x >> 3, kb = blockIdx.x & 7;
    int k = (kb << 8) + threadIdx.x;
    const float4* row = (const float4*)(cb + (size_t)(h * KK + k) * DD);
    float* ct = ws + WS_CT + (size_t)h * DD * KK + k;
    float s = 0.f;
#pragma unroll
    for (int p = 0; p < 16; ++p) {
        float4 v = row[p];
        s = fmaf(v.x, v.x, s); s = fmaf(v.y, v.y, s);
        s = fmaf(v.z, v.z, s); s = fmaf(v.w, v.w, s);
        int d = p * 4;
        ct[(size_t)(d + 0) * KK] = v.x;
        ct[(size_t)(d + 1) * KK] = v.y;
        ct[(size_t)(d + 2) * KK] = v.z;
        ct[(size_t)(d + 3) * KK] = v.w;
    }
    ws[WS_CSQ + h * KK + k] = s;
}

// ---------------- k1: h1=gelu(z@w1+b1); zh=h1@w2+b2; LayerNorm -> z_heads, zsq ----------------
__global__ __launch_bounds__(256, 2) void k1(const float* __restrict__ z, const float* __restrict__ w1,
                                             const float* __restrict__ b1, const float* __restrict__ w2,
                                             const float* __restrict__ b2, const float* __restrict__ lng,
                                             const float* __restrict__ lnb, float* __restrict__ out,
                                             float* __restrict__ ws) {
    // phase1: ztT[64k][68] (4352) + w1t[64k][128] (8192) = 12544 floats
    // phase2: h1t[64][128 swizzled] (8192) + w2t[128][64] (8192) = 16384 floats
    __shared__ float smem[16384];
    float* ztT = smem;
    float* w1t = smem + 4352;
    int t = threadIdx.x;
    int h = blockIdx.y;
    int b0 = blockIdx.x * 64;
    int cg = t & 15, rg = t >> 4; // GEMM1: rows rg*4+[0,4), cols cg*8+[0,8)

    float acc[4][8];
#pragma unroll
    for (int i = 0; i < 4; ++i)
#pragma unroll
        for (int j = 0; j < 8; ++j) acc[i][j] = 0.f;

    for (int kc = 0; kc < HIDN; kc += 64) {
        __syncthreads();
        // stage z transposed: ztT[k_local][row]
#pragma unroll
        for (int p = 0; p < 4; ++p) {
            int q = t + 256 * p;          // float4 id 0..1023
            int r = q >> 4, c4 = q & 15;
            float4 v = *(const float4*)(z + (size_t)(b0 + r) * HIDN + kc + c4 * 4);
            ztT[(c4 * 4 + 0) * 68 + r] = v.x;
            ztT[(c4 * 4 + 1) * 68 + r] = v.y;
            ztT[(c4 * 4 + 2) * 68 + r] = v.z;
            ztT[(c4 * 4 + 3) * 68 + r] = v.w;
        }
        // stage w1 rows kc..kc+63 (row-major [64][128])
#pragma unroll
        for (int p = 0; p < 8; ++p) {
            int q = t + 256 * p;          // float4 id 0..2047
            int r = q >> 5, c4 = q & 31;
            *(float4*)(w1t + r * 128 + c4 * 4) =
                *(const float4*)(w1 + (size_t)(h * HIDN + kc + r) * TWO_D + c4 * 4);
        }
        __syncthreads();
#pragma unroll 8
        for (int k = 0; k < 64; ++k) {
            float4 zv = *(const float4*)(ztT + k * 68 + rg * 4);
            float4 wa = *(const float4*)(w1t + k * 128 + cg * 8);
            float4 wb = *(const float4*)(w1t + k * 128 + cg * 8 + 4);
            float zz[4] = {zv.x, zv.y, zv.z, zv.w};
            float ww[8] = {wa.x, wa.y, wa.z, wa.w, wb.x, wb.y, wb.z, wb.w};
#pragma unroll
            for (int i = 0; i < 4; ++i)
#pragma unroll
                for (int j = 0; j < 8; ++j) acc[i][j] = fmaf(zz[i], ww[j], acc[i][j]);
        }
    }
    __syncthreads();
    // bias + exact gelu, write swizzled h1t
    float* h1t = smem;
    float* w2t = smem + 8192;
    int wswz = (rg & 7) << 2;
#pragma unroll
    for (int i = 0; i < 4; ++i)
#pragma unroll
        for (int j = 0; j < 8; ++j) {
            int c = cg * 8 + j;
            float x = acc[i][j] + b1[h * TWO_D + c];
            float gl = 0.5f * x * (1.0f + erff(x * 0.70710678118654752f));
            h1t[(rg * 4 + i) * 128 + (c ^ wswz)] = gl;
        }
    // stage w2 [128][64]
#pragma unroll
    for (int p = 0; p < 8; ++p) {
        int q = t + 256 * p;
        int r = q >> 4, c4 = q & 15;
        *(float4*)(w2t + r * 64 + c4 * 4) =
            *(const float4*)(w2 + (size_t)(h * TWO_D + r) * DD + c4 * 4);
    }
    __syncthreads();

    // GEMM2: rows rg2*4+[0,4), cols cg2*4+[0,4)
    int rg2 = t >> 4, cg2 = t & 15;
    int myswz = (rg2 & 7) << 2;
    float a2[4][4];
#pragma unroll
    for (int i = 0; i < 4; ++i)
#pragma unroll
        for (int j = 0; j < 4; ++j) a2[i][j] = 0.f;
#pragma unroll 4
    for (int i = 0; i < 128; ++i) {
        int ic = i ^ myswz;
        float hv[4];
#pragma unroll
        for (int rr = 0; rr < 4; ++rr) hv[rr] = h1t[(rg2 * 4 + rr) * 128 + ic];
        float4 wv = *(const float4*)(w2t + i * 64 + cg2 * 4);
        float ww[4] = {wv.x, wv.y, wv.z, wv.w};
#pragma unroll
        for (int rr = 0; rr < 4; ++rr)
#pragma unroll
            for (int jj = 0; jj < 4; ++jj) a2[rr][jj] = fmaf(hv[rr], ww[jj], a2[rr][jj]);
    }
    // wait: GEMM2 read swizzle must use col index i of h1 (stored at col i^swz(row)).
    // h1t element (r, c) stored at col c ^ ((r>>2)&7)<<2; reader's row r=rg2*4+rr -> swz=myswz; reads col i -> i^myswz. OK.

#pragma unroll
    for (int rr = 0; rr < 4; ++rr)
#pragma unroll
        for (int jj = 0; jj < 4; ++jj) a2[rr][jj] += b2[h * DD + cg2 * 4 + jj];

    // LayerNorm per row (16 lanes per row share it)
#pragma unroll
    for (int rr = 0; rr < 4; ++rr) {
        float sloc = a2[rr][0] + a2[rr][1] + a2[rr][2] + a2[rr][3];
#pragma unroll
        for (int m = 1; m < 16; m <<= 1) sloc += __shfl_xor(sloc, m, 64);
        float muv = sloc * (1.0f / 64.0f);
        float v0 = 0.f;
#pragma unroll
        for (int jj = 0; jj < 4; ++jj) { float dv = a2[rr][jj] - muv; v0 = fmaf(dv, dv, v0); }
#pragma unroll
        for (int m = 1; m < 16; m <<= 1) v0 += __shfl_xor(v0, m, 64);
        float var = v0 * (1.0f / 64.0f);
        float rstd = 1.0f / sqrtf(var + 1e-5f);
        int row = b0 + rg2 * 4 + rr;
        float zn[4]; float ss = 0.f;
#pragma unroll
        for (int jj = 0; jj < 4; ++jj) {
            int c = cg2 * 4 + jj;
            float v = (a2[rr][jj] - muv) * rstd * lng[h * DD + c] + lnb[h * DD + c];
            zn[jj] = v; ss = fmaf(v, v, ss);
        }
#pragma unroll
        for (int m = 1; m < 16; m <<= 1) ss += __shfl_xor(ss, m, 64);
        if (cg2 == 0) ws[WS_ZSQ + row * H + h] = ss;
        float4 sv = {zn[0], zn[1], zn[2], zn[3]};
        *(float4*)(out + OUT_ZH + (size_t)(row * H + h) * DD + cg2 * 4) = sv;
    }
}

// ---------------- k2: dists, argmin, online softmax, avg_probs, hist ----------------
__global__ __launch_bounds__(256, 4) void k2(float* __restrict__ out, float* __restrict__ ws) {
    int t = threadIdx.x;
    int h = blockIdx.y;
    int b0 = blockIdx.x * 64;
    const float* ct = ws + WS_CT + (size_t)h * DD * KK;
    const float* zh = out + OUT_ZH;
    float csqv[8], pacc[8];
#pragma unroll
    for (int jc = 0; jc < 8; ++jc) {
        csqv[jc] = ws[WS_CSQ + h * KK + jc * 256 + t];
        pacc[jc] = 0.f;
    }
    __shared__ float zt[8][64];
    __shared__ float zsqs[8];
    __shared__ float redM[8][4];
    __shared__ float redS[8][4];
    __shared__ int redK[8][4];

    for (int tile = 0; tile < 8; ++tile) {
        int rb = b0 + tile * 8;
        __syncthreads();
#pragma unroll
        for (int p = 0; p < 2; ++p) {
            int i = t + 256 * p;
            int r = i >> 6, d = i & 63;
            zt[r][d] = zh[(size_t)((rb + r) * H + h) * DD + d];
        }
        if (t < 8) zsqs[t] = ws[WS_ZSQ + (rb + t) * H + h];
        __syncthreads();

        float zc[8][8];
#pragma unroll
        for (int r = 0; r < 8; ++r)
#pragma unroll
            for (int jc = 0; jc < 8; ++jc) zc[r][jc] = 0.f;

#pragma unroll 2
        for (int d = 0; d < 64; ++d) {
            const float* cp = ct + (size_t)d * KK + t;
            float cv[8];
#pragma unroll
            for (int jc = 0; jc < 8; ++jc) cv[jc] = cp[jc * 256];
            float zv[8];
#pragma unroll
            for (int r = 0; r < 8; ++r) zv[r] = zt[r][d];
#pragma unroll
            for (int r = 0; r < 8; ++r)
#pragma unroll
                for (int jc = 0; jc < 8; ++jc) zc[r][jc] = fmaf(zv[r], cv[jc], zc[r][jc]);
        }
        // dists (reference formula: (z_sq + c_sq) - 2*zc)
#pragma unroll
        for (int r = 0; r < 8; ++r)
#pragma unroll
            for (int jc = 0; jc < 8; ++jc) zc[r][jc] = (zsqs[r] + csqv[jc]) - 2.0f * zc[r][jc];

        // per-row: thread-local min/argmin + online sum, then wave butterfly
#pragma unroll
        for (int r = 0; r < 8; ++r) {
            float mv = zc[r][0]; int mk = t;
#pragma unroll
            for (int jc = 1; jc < 8; ++jc) {
                if (zc[r][jc] < mv) { mv = zc[r][jc]; mk = jc * 256 + t; }
            }
            float s = 0.f;
#pragma unroll
            for (int jc = 0; jc < 8; ++jc) s += __expf(mv - zc[r][jc]);
#pragma unroll
            for (int off = 1; off < 64; off <<= 1) {
                float om = __shfl_xor(mv, off);
                float os = __shfl_xor(s, off);
                int ok = __shfl_xor(mk, off);
                if (om < mv || (om == mv && ok < mk)) {
                    s = os + s * __expf(om - mv); mv = om; mk = ok;
                } else {
                    s = s + os * __expf(mv - om);
                }
            }
            if ((t & 63) == 0) { int w = t >> 6; redM[r][w] = mv; redS[r][w] = s; redK[r][w] = mk; }
        }
        __syncthreads();
#pragma unroll
        for (int r = 0; r < 8; ++r) {
            float M = redM[r][0], S = redS[r][0]; int KI = redK[r][0];
#pragma unroll
            for (int w = 1; w < 4; ++w) {
                float om = redM[r][w], os = redS[r][w]; int ok = redK[r][w];
                if (om < M || (om == M && ok < KI)) { S = os + S * __expf(om - M); M = om; KI = ok; }
                else S += os * __expf(M - om);
            }
            float inv = 1.0f / S;
#pragma unroll
            for (int jc = 0; jc < 8; ++jc) pacc[jc] = fmaf(__expf(M - zc[r][jc]), inv, pacc[jc]);
            if (t == 0) {
                out[OUT_IDX + (rb + r) * H + h] = (float)KI;
                ((int*)ws)[WS_IDX + (rb + r) * H + h] = KI;
                atomicAdd(((unsigned*)ws) + WS_HIST + h * KK + KI, 1u);
            }
        }
    }
#pragma unroll
    for (int jc = 0; jc < 8; ++jc)
        atomicAdd(ws + WS_AVGP + h * KK + jc * 256 + t, pacc[jc]);
}

// ---------------- k3: decode z_q and z_heads, z_q_st output, commit accum ----------------
__global__ __launch_bounds__(256, 2) void k3(const float* __restrict__ cb, const float* __restrict__ dw,
                                             const float* __restrict__ db, float* __restrict__ out,
                                             float* __restrict__ ws) {
    __shared__ float zqt[32][65];
    __shared__ float zht[32][65];
    __shared__ float dwt[64][128];
    __shared__ int idxs[32];
    __shared__ double redc[4];
    int t = threadIdx.x;
    int h = blockIdx.y;
    int b0 = blockIdx.x * 32;
    if (t < 32) idxs[t] = ((const int*)ws)[WS_IDX + (b0 + t) * H + h];
    __syncthreads();
#pragma unroll
    for (int p = 0; p < 8; ++p) {
        int q = t + 256 * p;        // 2048 elements
        int r = q >> 6, d = q & 63;
        zqt[r][d] = cb[(size_t)(h * KK + idxs[r]) * DD + d];
        zht[r][d] = out[OUT_ZH + (size_t)((b0 + r) * H + h) * DD + d];
    }
#pragma unroll
    for (int p = 0; p < 8; ++p) {
        int q = t + 256 * p;        // 2048 float4
        int r = q >> 5, c4 = q & 31;
        *(float4*)(&dwt[r][c4 * 4]) = *(const float4*)(dw + (size_t)(h * DD + r) * OO + c4 * 4);
    }
    __syncthreads();
    int rg = t >> 4, cg = t & 15;   // rows rg*2+[0,2), cols cg*8+[0,8)
    float aq[2][8], ap[2][8];
#pragma unroll
    for (int i = 0; i < 2; ++i)
#pragma unroll
        for (int j = 0; j < 8; ++j) { aq[i][j] = 0.f; ap[i][j] = 0.f; }
#pragma unroll 4
    for (int d = 0; d < 64; ++d) {
        float q0 = zqt[rg * 2][d], q1 = zqt[rg * 2 + 1][d];
        float p0 = zht[rg * 2][d], p1 = zht[rg * 2 + 1][d];
        float4 wa = *(const float4*)(&dwt[d][cg * 8]);
        float4 wb = *(const float4*)(&dwt[d][cg * 8 + 4]);
        float ww[8] = {wa.x, wa.y, wa.z, wa.w, wb.x, wb.y, wb.z, wb.w};
#pragma unroll
        for (int j = 0; j < 8; ++j) {
            aq[0][j] = fmaf(q0, ww[j], aq[0][j]);
            aq[1][j] = fmaf(q1, ww[j], aq[1][j]);
            ap[0][j] = fmaf(p0, ww[j], ap[0][j]);
            ap[1][j] = fmaf(p1, ww[j], ap[1][j]);
        }
    }
    float lsum = 0.f;
#pragma unroll
    for (int i = 0; i < 2; ++i) {
        float vq4[8];
#pragma unroll
        for (int j = 0; j < 8; ++j) {
            float bb = db[h * OO + cg * 8 + j];
            float vq = aq[i][j] + bb;
            float vp = ap[i][j] + bb;
            // z_q_st = z_proj + (z_q_dec - z_proj), mimic fp order
            vq4[j] = vp + (vq - vp);
            float e = vp - vq;
            lsum = fmaf(e, e, lsum);
        }
        float4 s0 = {vq4[0], vq4[1], vq4[2], vq4[3]};
        float4 s1 = {vq4[4], vq4[5], vq4[6], vq4[7]};
        size_t o = (size_t)(b0 + rg * 2 + i) * HIDN + h * OO + cg * 8;
        *(float4*)(out + OUT_ZQ + o) = s0;
        *(float4*)(out + OUT_ZQ + o + 4) = s1;
    }
#pragma unroll
    for (int off = 1; off < 64; off <<= 1) lsum += __shfl_xor(lsum, off);
    if ((t & 63) == 0) redc[t >> 6] = (double)lsum;
    __syncthreads();
    if (t == 0) atomicAdd((double*)(ws + WS_ACC), redc[0] + redc[1] + redc[2] + redc[3]);
}

// ---------------- k6: ortho via LDS hash of co-occurrence pairs ----------------
__global__ __launch_bounds__(256) void k6(float* __restrict__ ws) {
    __shared__ unsigned slots[16384];
    __shared__ unsigned cnts[16384];
    int t = threadIdx.x;
    int bid = blockIdx.x;
    int pi = 0, pj = 1;
    {
        int c = 0;
        for (int a = 0; a < H; ++a)
            for (int b = a + 1; b < H; ++b) { if (c == bid) { pi = a; pj = b; } ++c; }
    }
    for (int s = t; s < 16384; s += 256) { slots[s] = 0xFFFFFFFFu; cnts[s] = 0u; }
    __syncthreads();
    const int* idxi = ((const int*)ws) + WS_IDX;
    for (int b = t; b < BB; b += 256) {
        unsigned key = ((unsigned)idxi[b * H + pi] << 11) | (unsigned)idxi[b * H + pj];
        unsigned p = (key * 2654435761u) >> 18;
        while (true) {
            unsigned old = atomicCAS(&slots[p], 0xFFFFFFFFu, key);
            if (old == 0xFFFFFFFFu || old == key) { atomicAdd(&cnts[p], 1u); break; }
            p = (p + 1) & 16383u;
        }
    }
    __syncthreads();
    const unsigned* hist = ((const unsigned*)ws) + WS_HIST;
    double loc = 0.0;
    for (int s = t; s < 16384; s += 256) {
        unsigned key = slots[s];
        if (key != 0xFFFFFFFFu) {
            int ki = (int)(key >> 11), kj = (int)(key & 2047u);
            float c = (float)cnts[s] * (1.0f / 8192.0f);
            float piv = (float)hist[pi * KK + ki] * (1.0f / 8192.0f);
            float pjv = (float)hist[pj * KK + kj] * (1.0f / 8192.0f);
            float e = piv * pjv;
            loc += (double)fabsf(c - e) - (double)e;
        }
    }
    double spi = 0.0, spj = 0.0;
    for (int k = t; k < KK; k += 256) {
        spi += (double)hist[pi * KK + k];
        spj += (double)hist[pj * KK + k];
    }
#pragma unroll
    for (int off = 1; off < 64; off <<= 1) {
        loc += __shfl_xor(loc, off);
        spi += __shfl_xor(spi, off);
        spj += __shfl_xor(spj, off);
    }
    __syncthreads();
    double* sc = (double*)cnts;
    if ((t & 63) == 0) { int w = t >> 6; sc[w] = loc; sc[4 + w] = spi; sc[8 + w] = spj; }
    __syncthreads();
    if (t == 0) {
        double L = sc[0] + sc[1] + sc[2] + sc[3];
        double SPI = (sc[4] + sc[5] + sc[6] + sc[7]) / 8192.0;
        double SPJ = (sc[8] + sc[9] + sc[10] + sc[11]) / 8192.0;
        atomicAdd(((double*)(ws + WS_ACC)) + 1, L + SPI * SPJ);
    }
}

// ---------------- k4: entropy_loss + scalar finalize ----------------
__global__ __launch_bounds__(256) void k4(float* __restrict__ out, float* __restrict__ ws) {
    __shared__ double red[256];
    int t = threadIdx.x;
    double tot = 0.0;
    for (int h = 0; h < H; ++h) {
        double s = 0.0;
        for (int k = t; k < KK; k += 256) {
            double a = (double)ws[WS_AVGP + h * KK + k] / 8192.0;
            s += a * log(a + 1e-8);
        }
        tot += s;
    }
    red[t] = tot;
    __syncthreads();
    for (int off = 128; off; off >>= 1) {
        if (t < off) red[t] += red[t + off];
        __syncthreads();
    }
    if (t == 0) {
        double entropy = -red[0] / 8.0;
        out[OUT_ENT] = (float)(1.0 - entropy / log(2048.0));
        double ca = *(const double*)(ws + WS_ACC);
        float cm = (float)(ca / (8192.0 * 1024.0));
        out[OUT_COMMIT] = cm;
        out[OUT_CBL] = cm;
        double oa = *(((const double*)(ws + WS_ACC)) + 1);
        out[OUT_ORTHO] = (float)(oa / (28.0 * 4194304.0));
    }
}

extern "C" void kernel_launch(void* const* d_in, const int* in_sizes, int n_in,
                              void* d_out, int out_size, void* d_ws, size_t ws_size,
                              hipStream_t stream) {
    (void)in_sizes; (void)n_in; (void)out_size; (void)ws_size;
    const float* z   = (const float*)d_in[0];
    const float* w1  = (const float*)d_in[1];
    const float* b1  = (const float*)d_in[2];
    const float* w2  = (const float*)d_in[3];
    const float* b2  = (const float*)d_in[4];
    const float* lng = (const float*)d_in[5];
    const float* lnb = (const float*)d_in[6];
    const float* cb  = (const float*)d_in[7];
    const float* dw  = (const float*)d_in[8];
    const float* db  = (const float*)d_in[9];
    float* out = (float*)d_out;
    float* ws = (float*)d_ws;

    hipMemsetAsync(ws + WS_AVGP, 0, WS_ZERO_BYTES, stream);
    k_pre<<<64, 256, 0, stream>>>(cb, ws);
    k1<<<dim3(128, 8), 256, 0, stream>>>(z, w1, b1, w2, b2, lng, lnb, out, ws);
    k2<<<dim3(128, 8), 256, 0, stream>>>(out, ws);
    k3<<<dim3(256, 8), 256, 0, stream>>>(cb, dw, db, out, ws);
    k6<<<28, 256, 0, stream>>>(ws);
    k4<<<1, 256, 0, stream>>>(out, ws);
}